// Round 1
// baseline (692.192 us; speedup 1.0000x reference)
//
#include <hip/hip_runtime.h>

#define T_Q   2048
#define N_REF 16384
#define DIM   768
#define BM    64
#define BN    256
#define BK    16
#define NLISTS (N_REF / BN)   // 64 partial lists per query

// ---------- small lexicographic top-4 helpers (static indices only) ----------

__device__ __forceinline__ bool lex_less(float sa, int ia, float sb, int ib) {
  return (sa < sb) || (sa == sb && ia < ib);
}

// compare-exchange: after call, (s0,i0) <= (s1,i1) lexicographically
#define CE_PAIR(s0, i0, s1, i1)                                        \
  { if (lex_less(s1, i1, s0, i0)) { float _ts = s0; s0 = s1; s1 = _ts; \
                                    int _ti = i0; i0 = i1; i1 = _ti; } }

#define PICKMIN(as, ai, bs, bi, rs, ri)                   \
  { if (lex_less(bs, bi, as, ai)) { rs = bs; ri = bi; }   \
    else                          { rs = as; ri = ai; } }

// insert candidate into sorted(asc) 4-list
__device__ __forceinline__ void insert4(float s[4], int id[4], float sc, int n) {
  if (lex_less(sc, n, s[3], id[3])) {
    s[3] = sc; id[3] = n;
    CE_PAIR(s[2], id[2], s[3], id[3]);
    CE_PAIR(s[1], id[1], s[2], id[2]);
    CE_PAIR(s[0], id[0], s[1], id[1]);
  }
}

// merge two sorted(asc) 4-lists, keep smallest 4 (bitonic lower-half + merge net)
__device__ __forceinline__ void merge_top4(float s[4], int id[4],
                                           const float os[4], const int oid[4]) {
  float l0, l1, l2, l3; int j0, j1, j2, j3;
  PICKMIN(s[0], id[0], os[3], oid[3], l0, j0);
  PICKMIN(s[1], id[1], os[2], oid[2], l1, j1);
  PICKMIN(s[2], id[2], os[1], oid[1], l2, j2);
  PICKMIN(s[3], id[3], os[0], oid[0], l3, j3);
  CE_PAIR(l0, j0, l2, j2);
  CE_PAIR(l1, j1, l3, j3);
  CE_PAIR(l0, j0, l1, j1);
  CE_PAIR(l2, j2, l3, j3);
  s[0] = l0; s[1] = l1; s[2] = l2; s[3] = l3;
  id[0] = j0; id[1] = j1; id[2] = j2; id[3] = j3;
}

// ---------- kernel 1: r2[n] = ||ref_n||^2 ----------
__global__ __launch_bounds__(256)
void r2_kernel(const float* __restrict__ R, float* __restrict__ r2) {
  __shared__ float red[256];
  const int lane = threadIdx.x & 63;
  const int dg   = threadIdx.x >> 6;          // 4 d-groups of 192
  const int n    = blockIdx.x * 64 + lane;
  float acc = 0.f;
  const int d0 = dg * (DIM / 4), d1 = d0 + (DIM / 4);
  for (int d = d0; d < d1; ++d) {
    float v = R[(size_t)d * N_REF + n];
    acc += v * v;
  }
  red[threadIdx.x] = acc;
  __syncthreads();
  if (threadIdx.x < 64)
    r2[n] = red[lane] + red[lane + 64] + red[lane + 128] + red[lane + 192];
}

// ---------- kernel 2: tiled fp32 GEMM (cross) + fused partial top-4 ----------
__global__ __launch_bounds__(256)
void score_topk_kernel(const float* __restrict__ X, const float* __restrict__ R,
                       const float* __restrict__ r2,
                       float* __restrict__ pscore, int* __restrict__ pidx) {
  __shared__ float As[BK][BM];    // 16 x 64  (4 KB)
  __shared__ float Bs[BK][BN];    // 16 x 256 (16 KB)
  __shared__ float r2s[BN];

  const int tid = threadIdx.x;
  const int tx = tid & 15, ty = tid >> 4;
  const int m0 = blockIdx.y * BM;
  const int n0 = blockIdx.x * BN;

  r2s[tid] = r2[n0 + tid];

  float acc[4][16];
#pragma unroll
  for (int i = 0; i < 4; ++i)
#pragma unroll
    for (int j = 0; j < 16; ++j) acc[i][j] = 0.f;

  for (int k0 = 0; k0 < DIM; k0 += BK) {
    // stage A: 16x64 floats = 256 float4, one per thread
    {
      const int k = tid >> 4, m4 = tid & 15;
      const float4 a = *(const float4*)&X[(size_t)(k0 + k) * T_Q + m0 + m4 * 4];
      *(float4*)&As[k][m4 * 4] = a;
    }
    // stage B: 16x256 floats = 1024 float4, four per thread
#pragma unroll
    for (int i = 0; i < 4; ++i) {
      const int idx4 = tid + i * 256;
      const int k = idx4 >> 6, n4 = idx4 & 63;
      const float4 b = *(const float4*)&R[(size_t)(k0 + k) * N_REF + n0 + n4 * 4];
      *(float4*)&Bs[k][n4 * 4] = b;
    }
    __syncthreads();
#pragma unroll
    for (int k = 0; k < BK; ++k) {
      float a[4], b[16];
      *(float4*)a = *(const float4*)&As[k][ty * 4];
#pragma unroll
      for (int c = 0; c < 4; ++c)
        *(float4*)&b[c * 4] = *(const float4*)&Bs[k][tx * 4 + c * 64];
#pragma unroll
      for (int mi = 0; mi < 4; ++mi)
#pragma unroll
        for (int ni = 0; ni < 16; ++ni) acc[mi][ni] += a[mi] * b[ni];
    }
    __syncthreads();
  }

  // epilogue: per query row, top-4 over this block's 256 columns
#pragma unroll
  for (int mi = 0; mi < 4; ++mi) {
    float s[4]  = {1e30f, 1e30f, 1e30f, 1e30f};
    int   id[4] = {0x7fffffff, 0x7fffffff, 0x7fffffff, 0x7fffffff};
#pragma unroll
    for (int c = 0; c < 4; ++c)
#pragma unroll
      for (int j = 0; j < 4; ++j) {
        const int nl = tx * 4 + c * 64 + j;
        const float sc = r2s[nl] - 2.0f * acc[mi][c * 4 + j];
        insert4(s, id, sc, n0 + nl);
      }
    // butterfly merge across the 16 lanes sharing this query row
#pragma unroll
    for (int mask = 1; mask < 16; mask <<= 1) {
      float os[4]; int oid[4];
#pragma unroll
      for (int j = 0; j < 4; ++j) {
        os[j]  = __shfl_xor(s[j], mask);
        oid[j] = __shfl_xor(id[j], mask);
      }
      merge_top4(s, id, os, oid);
    }
    if (tx == 0) {
      const int t = m0 + ty * 4 + mi;
      const int base = (t * NLISTS + (int)blockIdx.x) * 4;
#pragma unroll
      for (int j = 0; j < 4; ++j) { pscore[base + j] = s[j]; pidx[base + j] = id[j]; }
    }
  }
}

// ---------- kernel 3: reduce 64 partial lists per query -> final 4 indices ----------
__global__ __launch_bounds__(64)
void select_kernel(const float* __restrict__ pscore, const int* __restrict__ pidx,
                   int* __restrict__ final4) {
  const int t = blockIdx.x, lane = threadIdx.x;
  const int base = (t * NLISTS + lane) * 4;
  const float4 sv = *(const float4*)&pscore[base];
  const int4   iv = *(const int4*)&pidx[base];
  float s[4]  = {sv.x, sv.y, sv.z, sv.w};
  int   id[4] = {iv.x, iv.y, iv.z, iv.w};
#pragma unroll
  for (int mask = 1; mask < 64; mask <<= 1) {
    float os[4]; int oid[4];
#pragma unroll
    for (int j = 0; j < 4; ++j) {
      os[j]  = __shfl_xor(s[j], mask);
      oid[j] = __shfl_xor(id[j], mask);
    }
    merge_top4(s, id, os, oid);
  }
  if (lane == 0) {
    int4 o; o.x = id[0]; o.y = id[1]; o.z = id[2]; o.w = id[3];
    *(int4*)&final4[t * 4] = o;
  }
}

// ---------- kernel 4: gather 4 neighbors, average, write [d][T] ----------
__global__ __launch_bounds__(256)
void gather_kernel(const float* __restrict__ R, const int* __restrict__ final4,
                   float* __restrict__ out) {
  __shared__ int ids[64][4];
  const int tx = threadIdx.x & 63, ty = threadIdx.x >> 6;
  const int t0 = blockIdx.x * 64;
  ((int*)ids)[threadIdx.x] = final4[t0 * 4 + threadIdx.x];
  __syncthreads();
  const int d = blockIdx.y * 4 + ty;
  const float* row = R + (size_t)d * N_REF;
  const float sum = row[ids[tx][0]] + row[ids[tx][1]] + row[ids[tx][2]] + row[ids[tx][3]];
  out[(size_t)d * T_Q + t0 + tx] = 0.25f * sum;
}

extern "C" void kernel_launch(void* const* d_in, const int* in_sizes, int n_in,
                              void* d_out, int out_size, void* d_ws, size_t ws_size,
                              hipStream_t stream) {
  const float* X = (const float*)d_in[0];   // [768][2048]
  const float* R = (const float*)d_in[1];   // [768][16384]
  float* out = (float*)d_out;               // [768][2048]

  char* w = (char*)d_ws;
  float* r2     = (float*)w;  w += (size_t)N_REF * sizeof(float);                 // 64 KB
  float* pscore = (float*)w;  w += (size_t)T_Q * NLISTS * 4 * sizeof(float);      // 2 MB
  int*   pidx   = (int*)w;    w += (size_t)T_Q * NLISTS * 4 * sizeof(int);        // 2 MB
  int*   final4 = (int*)w;                                                        // 32 KB

  hipLaunchKernelGGL(r2_kernel, dim3(N_REF / 64), dim3(256), 0, stream, R, r2);
  hipLaunchKernelGGL(score_topk_kernel, dim3(N_REF / BN, T_Q / BM), dim3(256), 0, stream,
                     X, R, r2, pscore, pidx);
  hipLaunchKernelGGL(select_kernel, dim3(T_Q), dim3(64), 0, stream, pscore, pidx, final4);
  hipLaunchKernelGGL(gather_kernel, dim3(T_Q / 64, DIM / 4), dim3(256), 0, stream,
                     R, final4, out);
}

// Round 2
// 277.158 us; speedup vs baseline: 2.4975x; 2.4975x over previous
//
#include <hip/hip_runtime.h>
#include <stdint.h>

#define T_Q   2048
#define N_REF 16384
#define DIM   768

using f16   = _Float16;
using f16x8 = __attribute__((ext_vector_type(8))) _Float16;
using f32x4 = __attribute__((ext_vector_type(4))) float;

// ---------- lexicographic top-4 helpers (static indices only) ----------
__device__ __forceinline__ bool lex_less(float sa, int ia, float sb, int ib) {
  return (sa < sb) || (sa == sb && ia < ib);
}
#define CE_PAIR(s0, i0, s1, i1)                                        \
  { if (lex_less(s1, i1, s0, i0)) { float _ts = s0; s0 = s1; s1 = _ts; \
                                    int _ti = i0; i0 = i1; i1 = _ti; } }
#define PICKMIN(as, ai, bs, bi, rs, ri)                   \
  { if (lex_less(bs, bi, as, ai)) { rs = bs; ri = bi; }   \
    else                          { rs = as; ri = ai; } }

__device__ __forceinline__ void insert4(float s[4], int id[4], float sc, int n) {
  if (lex_less(sc, n, s[3], id[3])) {
    s[3] = sc; id[3] = n;
    CE_PAIR(s[2], id[2], s[3], id[3]);
    CE_PAIR(s[1], id[1], s[2], id[2]);
    CE_PAIR(s[0], id[0], s[1], id[1]);
  }
}
__device__ __forceinline__ void merge_top4(float s[4], int id[4],
                                           const float os[4], const int oid[4]) {
  float l0, l1, l2, l3; int j0, j1, j2, j3;
  PICKMIN(s[0], id[0], os[3], oid[3], l0, j0);
  PICKMIN(s[1], id[1], os[2], oid[2], l1, j1);
  PICKMIN(s[2], id[2], os[1], oid[1], l2, j2);
  PICKMIN(s[3], id[3], os[0], oid[0], l3, j3);
  CE_PAIR(l0, j0, l2, j2);
  CE_PAIR(l1, j1, l3, j3);
  CE_PAIR(l0, j0, l1, j1);
  CE_PAIR(l2, j2, l3, j3);
  s[0] = l0; s[1] = l1; s[2] = l2; s[3] = l3;
  id[0] = j0; id[1] = j1; id[2] = j2; id[3] = j3;
}

__device__ __forceinline__ void gl_lds16(const void* g, void* l) {
  __builtin_amdgcn_global_load_lds((const __attribute__((address_space(1))) uint32_t*)g,
                                   (__attribute__((address_space(3))) uint32_t*)l, 16, 0, 0);
}

// ---------- kernel: r2[n] = ||ref_n||^2 (fp32 exact) ----------
__global__ __launch_bounds__(256)
void r2_kernel(const float* __restrict__ R, float* __restrict__ r2) {
  __shared__ float red[256];
  const int lane = threadIdx.x & 63;
  const int dg   = threadIdx.x >> 6;
  const int n    = blockIdx.x * 64 + lane;
  float acc = 0.f;
  const int d0 = dg * (DIM / 4), d1 = d0 + (DIM / 4);
  for (int d = d0; d < d1; ++d) {
    float v = R[(size_t)d * N_REF + n];
    acc += v * v;
  }
  red[threadIdx.x] = acc;
  __syncthreads();
  if (threadIdx.x < 64)
    r2[n] = red[lane] + red[lane + 64] + red[lane + 128] + red[lane + 192];
}

// ---------- kernel: transpose + fp16 hi/lo split:  in[D][W] -> oh/ol[W][D] ----------
__global__ __launch_bounds__(256)
void tsplit_kernel(const float* __restrict__ in, f16* __restrict__ oh,
                   f16* __restrict__ ol, int W) {
  __shared__ f16 lh[64][65], ll[64][65];
  const int c0 = blockIdx.x * 64, d0 = blockIdx.y * 64;
  const int cl = threadIdx.x & 63, dq = threadIdx.x >> 6;
#pragma unroll
  for (int i = 0; i < 16; ++i) {
    const int dl = i * 4 + dq;
    const float v = in[(size_t)(d0 + dl) * W + c0 + cl];
    const f16 h = (f16)v;
    const f16 l = (f16)(v - (float)h);
    lh[cl][dl] = h; ll[cl][dl] = l;
  }
  __syncthreads();
#pragma unroll
  for (int i = 0; i < 16; ++i) {
    const int rl = i * 4 + dq;
    oh[(size_t)(c0 + rl) * DIM + d0 + cl] = lh[rl][cl];
    ol[(size_t)(c0 + rl) * DIM + d0 + cl] = ll[rl][cl];
  }
}

// ---------- kernel: split-fp16 MFMA GEMM + fused partial top-4 ----------
// C[t][n] = sum_d X[t][d]*R[n][d] via 16x16x32_f16, 3 products (hh, hl, lh).
// Block: 256 thr = 4 waves (2m x 2n), tile BM=128 x BN=128, BK=32.
// Partial lists: per (query, 64-col wave stripe) -> NL = 256 lists/query.
#define BM 128
#define BN 128
#define BK 32
#define NL 256

__global__ __launch_bounds__(256)
void mfma_topk_kernel(const f16* __restrict__ Xh, const f16* __restrict__ Xl,
                      const f16* __restrict__ Rh, const f16* __restrict__ Rl,
                      const float* __restrict__ r2,
                      float* __restrict__ pscore, int* __restrict__ pidx) {
  // LDS map: [0,8K) Ah | [8K,16K) Al | [16K,24K) Bh | [24K,32K) Bl
  //          epilogue: per-wave [32][66] f32 at wid*8448 (0..33792) | r2s at 33792
  __shared__ __align__(16) char smem[34304];
  const int tid  = threadIdx.x;
  const int lane = tid & 63, wid = tid >> 6;
  const int wm = wid >> 1, wn = wid & 1;
  const int m0 = blockIdx.y * BM, n0 = blockIdx.x * BN;
  float* r2s = (float*)(smem + 33792);
  if (tid < BN) r2s[tid] = r2[n0 + tid];

  // staging descriptors: 8 x global_load_lds(dwordx4) per thread per K-step.
  // LDS linear slot s (16B): region r2=s>>9, idx=s&511, row=idx>>2, seg=idx&3.
  // XOR swizzle: LDS slot holds global seg' = seg ^ ((row>>1)&3)  (involution).
  const f16* gbase[8];
  char* lptr[8];
#pragma unroll
  for (int i = 0; i < 8; ++i) {
    const int slot = i * 256 + tid;
    const int region = slot >> 9;
    const int idx = slot & 511;
    const int row = idx >> 2, seg = idx & 3;
    const int segs = seg ^ ((row >> 1) & 3);
    const f16* base = (region == 0) ? (Xh + (size_t)(m0 + row) * DIM)
                    : (region == 1) ? (Xl + (size_t)(m0 + row) * DIM)
                    : (region == 2) ? (Rh + (size_t)(n0 + row) * DIM)
                                    : (Rl + (size_t)(n0 + row) * DIM);
    gbase[i] = base + segs * 8;
    lptr[i]  = smem + region * 8192 + idx * 16;
  }

  // fragment LDS byte offsets (K-invariant): row-major [row][32 f16] with slot-XOR
  int aof[4], bof[4];
  const int ln15 = lane & 15, g4 = lane >> 4;
#pragma unroll
  for (int i = 0; i < 4; ++i) {
    const int ra = wm * 64 + i * 16 + ln15;
    aof[i] = ra * 64 + ((g4 ^ (ra >> 1)) & 3) * 16;
    const int rb = wn * 64 + i * 16 + ln15;
    bof[i] = rb * 64 + ((g4 ^ (rb >> 1)) & 3) * 16;
  }

  f32x4 acc[4][4] = {};
  for (int k0 = 0; k0 < DIM; k0 += BK) {
#pragma unroll
    for (int i = 0; i < 8; ++i) gl_lds16(gbase[i] + k0, lptr[i]);
    __syncthreads();   // emits vmcnt(0) drain + barrier
    f16x8 ah[4], al[4], bh[4], bl[4];
#pragma unroll
    for (int i = 0; i < 4; ++i) {
      ah[i] = *(const f16x8*)(smem + aof[i]);
      al[i] = *(const f16x8*)(smem + 8192 + aof[i]);
      bh[i] = *(const f16x8*)(smem + 16384 + bof[i]);
      bl[i] = *(const f16x8*)(smem + 24576 + bof[i]);
    }
#pragma unroll
    for (int mi = 0; mi < 4; ++mi)
#pragma unroll
      for (int ni = 0; ni < 4; ++ni) {
        acc[mi][ni] = __builtin_amdgcn_mfma_f32_16x16x32_f16(ah[mi], bh[ni], acc[mi][ni], 0, 0, 0);
        acc[mi][ni] = __builtin_amdgcn_mfma_f32_16x16x32_f16(ah[mi], bl[ni], acc[mi][ni], 0, 0, 0);
        acc[mi][ni] = __builtin_amdgcn_mfma_f32_16x16x32_f16(al[mi], bh[ni], acc[mi][ni], 0, 0, 0);
      }
    __syncthreads();
  }

  // ---------- epilogue: per-wave score matrix -> 1 lane per output row ----------
  __syncthreads();
  float rv[4];
#pragma unroll
  for (int ni = 0; ni < 4; ++ni) rv[ni] = r2s[wn * 64 + ni * 16 + ln15];
  float* sw = (float*)(smem + wid * 8448);  // [32][66] f32
#pragma unroll
  for (int p = 0; p < 2; ++p) {
    // scatter scores: C/D layout col=lane&15, row=(lane>>4)*4+reg  [m89/m91]
#pragma unroll
    for (int mh = 0; mh < 2; ++mh)
#pragma unroll
      for (int ni = 0; ni < 4; ++ni)
#pragma unroll
        for (int r = 0; r < 4; ++r) {
          const int mi = 2 * p + mh;
          const int row_l = mh * 16 + g4 * 4 + r;
          sw[row_l * 66 + ni * 16 + ln15] = rv[ni] - 2.0f * acc[mi][ni][r];
        }
    __syncthreads();
    // scan: 2 lanes per row, 32 cols each (b64 reads keep 2-way banks = free)
    const int rr = lane >> 1, hh = lane & 1;
    float s[4]  = {1e30f, 1e30f, 1e30f, 1e30f};
    int   id[4] = {0x7fffffff, 0x7fffffff, 0x7fffffff, 0x7fffffff};
    const float* rowp = sw + rr * 66 + hh * 32;
    const int cbase = n0 + wn * 64 + hh * 32;
#pragma unroll
    for (int j = 0; j < 16; ++j) {
      const float2 v = *(const float2*)(rowp + j * 2);
      insert4(s, id, v.x, cbase + j * 2);
      insert4(s, id, v.y, cbase + j * 2 + 1);
    }
    float os[4]; int oid[4];
#pragma unroll
    for (int j = 0; j < 4; ++j) {
      os[j]  = __shfl_xor(s[j], 1);
      oid[j] = __shfl_xor(id[j], 1);
    }
    merge_top4(s, id, os, oid);
    if (hh == 0) {
      const int q = m0 + wm * 64 + p * 32 + rr;
      const int base = (q * NL + (int)blockIdx.x * 2 + wn) * 4;
#pragma unroll
      for (int j = 0; j < 4; ++j) { pscore[base + j] = s[j]; pidx[base + j] = id[j]; }
    }
    __syncthreads();
  }
}

// ---------- kernel: merge NL partial lists per query -> final 4 indices ----------
template <int NLISTS>
__global__ __launch_bounds__(64)
void select_kernel(const float* __restrict__ pscore, const int* __restrict__ pidx,
                   int* __restrict__ final4) {
  const int t = blockIdx.x, lane = threadIdx.x;
  constexpr int LPL = NLISTS / 64;
  float s[4]  = {1e30f, 1e30f, 1e30f, 1e30f};
  int   id[4] = {0x7fffffff, 0x7fffffff, 0x7fffffff, 0x7fffffff};
#pragma unroll
  for (int li = 0; li < LPL; ++li) {
    const int base = (t * NLISTS + lane * LPL + li) * 4;
    const float4 sv = *(const float4*)&pscore[base];
    const int4   iv = *(const int4*)&pidx[base];
    float os[4] = {sv.x, sv.y, sv.z, sv.w};
    int  oid[4] = {iv.x, iv.y, iv.z, iv.w};
    merge_top4(s, id, os, oid);
  }
#pragma unroll
  for (int mask = 1; mask < 64; mask <<= 1) {
    float os[4]; int oid[4];
#pragma unroll
    for (int j = 0; j < 4; ++j) {
      os[j]  = __shfl_xor(s[j], mask);
      oid[j] = __shfl_xor(id[j], mask);
    }
    merge_top4(s, id, os, oid);
  }
  if (lane == 0) {
    int4 o; o.x = id[0]; o.y = id[1]; o.z = id[2]; o.w = id[3];
    *(int4*)&final4[t * 4] = o;
  }
}

// ---------- kernel: gather 4 neighbors, average, write [d][T] ----------
__global__ __launch_bounds__(256)
void gather_kernel(const float* __restrict__ R, const int* __restrict__ final4,
                   float* __restrict__ out) {
  __shared__ int ids[64][4];
  const int tx = threadIdx.x & 63, ty = threadIdx.x >> 6;
  const int t0 = blockIdx.x * 64;
  ((int*)ids)[threadIdx.x] = final4[t0 * 4 + threadIdx.x];
  __syncthreads();
  const int d = blockIdx.y * 4 + ty;
  const float* row = R + (size_t)d * N_REF;
  const float sum = row[ids[tx][0]] + row[ids[tx][1]] + row[ids[tx][2]] + row[ids[tx][3]];
  out[(size_t)d * T_Q + t0 + tx] = 0.25f * sum;
}

// ---------- fallback fp32 kernel (round-1, known correct) ----------
#define FBM 64
#define FBN 256
#define FBK 16
#define FNL (N_REF / FBN)
__global__ __launch_bounds__(256)
void score_topk_kernel(const float* __restrict__ X, const float* __restrict__ R,
                       const float* __restrict__ r2,
                       float* __restrict__ pscore, int* __restrict__ pidx) {
  __shared__ float As[FBK][FBM];
  __shared__ float Bs[FBK][FBN];
  __shared__ float r2s[FBN];
  const int tid = threadIdx.x;
  const int tx = tid & 15, ty = tid >> 4;
  const int m0 = blockIdx.y * FBM;
  const int n0 = blockIdx.x * FBN;
  r2s[tid] = r2[n0 + tid];
  float acc[4][16];
#pragma unroll
  for (int i = 0; i < 4; ++i)
#pragma unroll
    for (int j = 0; j < 16; ++j) acc[i][j] = 0.f;
  for (int k0 = 0; k0 < DIM; k0 += FBK) {
    {
      const int k = tid >> 4, m4 = tid & 15;
      const float4 a = *(const float4*)&X[(size_t)(k0 + k) * T_Q + m0 + m4 * 4];
      *(float4*)&As[k][m4 * 4] = a;
    }
#pragma unroll
    for (int i = 0; i < 4; ++i) {
      const int idx4 = tid + i * 256;
      const int k = idx4 >> 6, n4 = idx4 & 63;
      const float4 b = *(const float4*)&R[(size_t)(k0 + k) * N_REF + n0 + n4 * 4];
      *(float4*)&Bs[k][n4 * 4] = b;
    }
    __syncthreads();
#pragma unroll
    for (int k = 0; k < FBK; ++k) {
      float a[4], b[16];
      *(float4*)a = *(const float4*)&As[k][ty * 4];
#pragma unroll
      for (int c = 0; c < 4; ++c)
        *(float4*)&b[c * 4] = *(const float4*)&Bs[k][tx * 4 + c * 64];
#pragma unroll
      for (int mi = 0; mi < 4; ++mi)
#pragma unroll
        for (int ni = 0; ni < 16; ++ni) acc[mi][ni] += a[mi] * b[ni];
    }
    __syncthreads();
  }
#pragma unroll
  for (int mi = 0; mi < 4; ++mi) {
    float s[4]  = {1e30f, 1e30f, 1e30f, 1e30f};
    int   id[4] = {0x7fffffff, 0x7fffffff, 0x7fffffff, 0x7fffffff};
#pragma unroll
    for (int c = 0; c < 4; ++c)
#pragma unroll
      for (int j = 0; j < 4; ++j) {
        const int nl = tx * 4 + c * 64 + j;
        const float sc = r2s[nl] - 2.0f * acc[mi][c * 4 + j];
        insert4(s, id, sc, n0 + nl);
      }
#pragma unroll
    for (int mask = 1; mask < 16; mask <<= 1) {
      float os[4]; int oid[4];
#pragma unroll
      for (int j = 0; j < 4; ++j) {
        os[j]  = __shfl_xor(s[j], mask);
        oid[j] = __shfl_xor(id[j], mask);
      }
      merge_top4(s, id, os, oid);
    }
    if (tx == 0) {
      const int t = m0 + ty * 4 + mi;
      const int base = (t * FNL + (int)blockIdx.x) * 4;
#pragma unroll
      for (int j = 0; j < 4; ++j) { pscore[base + j] = s[j]; pidx[base + j] = id[j]; }
    }
  }
}

extern "C" void kernel_launch(void* const* d_in, const int* in_sizes, int n_in,
                              void* d_out, int out_size, void* d_ws, size_t ws_size,
                              hipStream_t stream) {
  const float* X = (const float*)d_in[0];   // [768][2048]
  const float* R = (const float*)d_in[1];   // [768][16384]
  float* out = (float*)d_out;               // [768][2048]

  // fast-path workspace layout (f16 split + transposed copies)
  const size_t szXh = (size_t)T_Q * DIM * sizeof(f16);      // 3,145,728
  const size_t szRh = (size_t)N_REF * DIM * sizeof(f16);    // 25,165,824
  const size_t szr2 = (size_t)N_REF * sizeof(float);        // 65,536
  const size_t szPS = (size_t)T_Q * NL * 4 * sizeof(float); // 8,388,608
  const size_t need = 2 * szXh + 2 * szRh + szr2 + 2 * szPS + (size_t)T_Q * 4 * sizeof(int);

  if (ws_size >= need) {
    char* w = (char*)d_ws;
    f16* Xh = (f16*)w;            w += szXh;
    f16* Xl = (f16*)w;            w += szXh;
    f16* Rh = (f16*)w;            w += szRh;
    f16* Rl = (f16*)w;            w += szRh;
    float* r2     = (float*)w;    w += szr2;
    float* pscore = (float*)w;    w += szPS;
    int*   pidx   = (int*)w;      w += szPS;
    int*   final4 = (int*)w;

    hipLaunchKernelGGL(r2_kernel, dim3(N_REF / 64), dim3(256), 0, stream, R, r2);
    hipLaunchKernelGGL(tsplit_kernel, dim3(T_Q / 64, DIM / 64), dim3(256), 0, stream,
                       X, Xh, Xl, T_Q);
    hipLaunchKernelGGL(tsplit_kernel, dim3(N_REF / 64, DIM / 64), dim3(256), 0, stream,
                       R, Rh, Rl, N_REF);
    hipLaunchKernelGGL(mfma_topk_kernel, dim3(N_REF / BN, T_Q / BM), dim3(256), 0, stream,
                       Xh, Xl, Rh, Rl, r2, pscore, pidx);
    hipLaunchKernelGGL((select_kernel<NL>), dim3(T_Q), dim3(64), 0, stream,
                       pscore, pidx, final4);
    hipLaunchKernelGGL(gather_kernel, dim3(T_Q / 64, DIM / 4), dim3(256), 0, stream,
                       R, final4, out);
  } else {
    // fallback: round-1 fp32 pipeline (~4.2 MB ws)
    char* w = (char*)d_ws;
    float* r2     = (float*)w;  w += szr2;
    float* pscore = (float*)w;  w += (size_t)T_Q * FNL * 4 * sizeof(float);
    int*   pidx   = (int*)w;    w += (size_t)T_Q * FNL * 4 * sizeof(int);
    int*   final4 = (int*)w;

    hipLaunchKernelGGL(r2_kernel, dim3(N_REF / 64), dim3(256), 0, stream, R, r2);
    hipLaunchKernelGGL(score_topk_kernel, dim3(N_REF / FBN, T_Q / FBM), dim3(256), 0, stream,
                       X, R, r2, pscore, pidx);
    hipLaunchKernelGGL((select_kernel<FNL>), dim3(T_Q), dim3(64), 0, stream,
                       pscore, pidx, final4);
    hipLaunchKernelGGL(gather_kernel, dim3(T_Q / 64, DIM / 4), dim3(256), 0, stream,
                       R, final4, out);
  }
}

// Round 3
// 268.209 us; speedup vs baseline: 2.5808x; 1.0334x over previous
//
#include <hip/hip_runtime.h>
#include <stdint.h>

#define T_Q   2048
#define N_REF 16384
#define DIM   768
#define KP2   1536        // packed K cols: [hi | lo]
#define NT    36          // logical K' = 2304 = 36 tiles of 64
#define BM    256
#define BN    256
#define NL    256         // partial top-4 lists per query

using f16   = _Float16;
using f16x4 = __attribute__((ext_vector_type(4))) _Float16;
using f16x8 = __attribute__((ext_vector_type(8))) _Float16;
using f32x4 = __attribute__((ext_vector_type(4))) float;

// ---------- lexicographic top-4 helpers (static indices only) ----------
__device__ __forceinline__ bool lex_less(float sa, int ia, float sb, int ib) {
  return (sa < sb) || (sa == sb && ia < ib);
}
#define CE_PAIR(s0, i0, s1, i1)                                        \
  { if (lex_less(s1, i1, s0, i0)) { float _ts = s0; s0 = s1; s1 = _ts; \
                                    int _ti = i0; i0 = i1; i1 = _ti; } }
#define PICKMIN(as, ai, bs, bi, rs, ri)                   \
  { if (lex_less(bs, bi, as, ai)) { rs = bs; ri = bi; }   \
    else                          { rs = as; ri = ai; } }

__device__ __forceinline__ void insert4(float s[4], int id[4], float sc, int n) {
  if (lex_less(sc, n, s[3], id[3])) {
    s[3] = sc; id[3] = n;
    CE_PAIR(s[2], id[2], s[3], id[3]);
    CE_PAIR(s[1], id[1], s[2], id[2]);
    CE_PAIR(s[0], id[0], s[1], id[1]);
  }
}
__device__ __forceinline__ void merge_top4(float s[4], int id[4],
                                           const float os[4], const int oid[4]) {
  float l0, l1, l2, l3; int j0, j1, j2, j3;
  PICKMIN(s[0], id[0], os[3], oid[3], l0, j0);
  PICKMIN(s[1], id[1], os[2], oid[2], l1, j1);
  PICKMIN(s[2], id[2], os[1], oid[1], l2, j2);
  PICKMIN(s[3], id[3], os[0], oid[0], l3, j3);
  CE_PAIR(l0, j0, l2, j2);
  CE_PAIR(l1, j1, l3, j3);
  CE_PAIR(l0, j0, l1, j1);
  CE_PAIR(l2, j2, l3, j3);
  s[0] = l0; s[1] = l1; s[2] = l2; s[3] = l3;
  id[0] = j0; id[1] = j1; id[2] = j2; id[3] = j3;
}

__device__ __forceinline__ void gl_lds16(const void* g, void* l) {
  __builtin_amdgcn_global_load_lds((const __attribute__((address_space(1))) uint32_t*)g,
                                   (__attribute__((address_space(3))) uint32_t*)l, 16, 0, 0);
}

// ---------- r2[n] = ||ref_n||^2 (fp32 exact) ----------
__global__ __launch_bounds__(256)
void r2_kernel(const float* __restrict__ R, float* __restrict__ r2) {
  __shared__ float red[256];
  const int lane = threadIdx.x & 63;
  const int dg   = threadIdx.x >> 6;
  const int n    = blockIdx.x * 64 + lane;
  float acc = 0.f;
  const int d0 = dg * (DIM / 4), d1 = d0 + (DIM / 4);
  for (int d = d0; d < d1; ++d) {
    float v = R[(size_t)d * N_REF + n];
    acc += v * v;
  }
  red[threadIdx.x] = acc;
  __syncthreads();
  if (threadIdx.x < 64)
    r2[n] = red[lane] + red[lane + 64] + red[lane + 128] + red[lane + 192];
}

// ---------- transpose + f16 hi/lo split: in[D][W] -> out[W][1536] = [hi | lo] ----------
__global__ __launch_bounds__(256)
void tsplit_kernel(const float* __restrict__ in, f16* __restrict__ out, int W) {
  __shared__ f16 lh[64][66], ll[64][66];
  const int c0 = blockIdx.x * 64, d0 = blockIdx.y * 64;
  const int q = threadIdx.x & 15, p = threadIdx.x >> 4;
#pragma unroll
  for (int i = 0; i < 4; ++i) {
    const int dl = p + i * 16;
    const float4 v = *(const float4*)&in[(size_t)(d0 + dl) * W + c0 + q * 4];
    const f16 h0 = (f16)v.x, h1 = (f16)v.y, h2 = (f16)v.z, h3 = (f16)v.w;
    lh[q * 4 + 0][dl] = h0; ll[q * 4 + 0][dl] = (f16)(v.x - (float)h0);
    lh[q * 4 + 1][dl] = h1; ll[q * 4 + 1][dl] = (f16)(v.y - (float)h1);
    lh[q * 4 + 2][dl] = h2; ll[q * 4 + 2][dl] = (f16)(v.z - (float)h2);
    lh[q * 4 + 3][dl] = h3; ll[q * 4 + 3][dl] = (f16)(v.w - (float)h3);
  }
  __syncthreads();
  const int rl = threadIdx.x >> 2, seg = threadIdx.x & 3;
  f16* rowo = out + (size_t)(c0 + rl) * KP2 + d0;
#pragma unroll
  for (int j = 0; j < 4; ++j) {
    const int dd = seg * 16 + j * 4;
    f16x4 vh = *(const f16x4*)&lh[rl][dd];
    f16x4 vl = *(const f16x4*)&ll[rl][dd];
    *(f16x4*)&rowo[dd] = vh;
    *(f16x4*)&rowo[768 + dd] = vl;
  }
}

// ---------- 8-phase-style 256x256 MFMA GEMM (K'=2304 folded) + fused top-4 ----------
__global__ __launch_bounds__(512, 2)
void mfma8_topk_kernel(const f16* __restrict__ A2, const f16* __restrict__ B2,
                       const float* __restrict__ r2g,
                       float* __restrict__ pscore, int* __restrict__ pidx) {
  // LDS: dbuf d at d*65536; within dbuf: A-ks0 @0, A-ks1 @16384, B-ks0 @32768, B-ks1 @49152
  // each region: 256 rows x 32 K-cols f16 (64B rows), 16B slots XOR-swizzled by (row&3)<<4
  __shared__ __align__(16) char smem[131072];
  const int tid  = threadIdx.x;
  const int lane = tid & 63, wid = tid >> 6;
  const int wm = wid >> 2, wn = wid & 3;
  const int ln15 = lane & 15, g4 = lane >> 4;

  // XCD-aware bijective swizzle (512 = 8*64)
  const int flat = (int)blockIdx.x;
  const int swz = (flat & 7) * 64 + (flat >> 3);
  const int bx = swz & 63, by = swz >> 6;
  const int m0 = by * BM, n0 = bx * BN;

  // ---- staging descriptors: 2 gl_lds(16B) per thread per half-tile ----
  const int s0 = tid, s1 = tid + 512;
  const int r0 = s0 >> 2, r1 = s1 >> 2;
  const int c0b = ((s0 & 3) << 4) ^ ((r0 & 3) << 4);  // inverse-swizzled global K-byte
  const int c1b = ((s1 & 3) << 4) ^ ((r1 & 3) << 4);
  const char* gA0 = (const char*)(A2 + (size_t)(m0 + r0) * KP2) + c0b;
  const char* gA1 = (const char*)(A2 + (size_t)(m0 + r1) * KP2) + c1b;
  const char* gB0 = (const char*)(B2 + (size_t)(n0 + r0) * KP2) + c0b;
  const char* gB1 = (const char*)(B2 + (size_t)(n0 + r1) * KP2) + c1b;
  const int l0 = s0 * 16, l1 = s1 * 16;  // linear LDS slot (wave-consecutive)

#define STAGE_A(sdb, regoff, kbyte)                              \
  { gl_lds16(gA0 + (kbyte), smem + (sdb) + (regoff) + l0);       \
    gl_lds16(gA1 + (kbyte), smem + (sdb) + (regoff) + l1); }
#define STAGE_B(sdb, regoff, kbyte)                              \
  { gl_lds16(gB0 + (kbyte), smem + (sdb) + (regoff) + l0);       \
    gl_lds16(gB1 + (kbyte), smem + (sdb) + (regoff) + l1); }

  // ---- fragment LDS offsets (K-invariant; add dbuf + ks*16384 at use) ----
  const int cswz = (g4 << 4) ^ ((ln15 & 3) << 4);
  int offA[8], offB[4];
#pragma unroll
  for (int mi = 0; mi < 8; ++mi) offA[mi] = (wm * 128 + mi * 16 + ln15) * 64 + cswz;
#pragma unroll
  for (int ni = 0; ni < 4; ++ni) offB[ni] = 32768 + (wn * 64 + ni * 16 + ln15) * 64 + cswz;

  f32x4 acc[8][4] = {};

  // prologue: stage kt=0 (dbuf0), order A0,B0,A1,B1
  STAGE_A(0, 0, 0);
  STAGE_B(0, 32768, 0);
  STAGE_A(0, 16384, 64);
  STAGE_B(0, 49152, 64);

  for (int kt = 0; kt < NT; ++kt) {
    const int dbuf = (kt & 1) << 16;
    const int sdb  = ((kt + 1) & 1) << 16;
    const int ktn = kt + 1;
    int tA = ktn < 12 ? ktn : ktn - 12; tA = tA > 23 ? 23 : tA;      // [Xh|Xh|Xl] map
    const int tB = ktn < 24 ? ktn : ktn - 24;                        // [Rh|Rl|Rh] map
    const int kbA = tA * 128, kbB = tB * 128;
    f16x8 a[8], b[4];

    // ---- phase 0: ks0, ni 0-1 ----
    asm volatile("s_waitcnt vmcnt(4)" ::: "memory");
    asm volatile("s_barrier" ::: "memory");
#pragma unroll
    for (int mi = 0; mi < 8; ++mi) a[mi] = *(const f16x8*)(smem + dbuf + offA[mi]);
    b[0] = *(const f16x8*)(smem + dbuf + offB[0]);
    b[1] = *(const f16x8*)(smem + dbuf + offB[1]);
    STAGE_A(sdb, 0, kbA);
    __builtin_amdgcn_s_setprio(1);
#pragma unroll
    for (int mi = 0; mi < 8; ++mi) {
      acc[mi][0] = __builtin_amdgcn_mfma_f32_16x16x32_f16(a[mi], b[0], acc[mi][0], 0, 0, 0);
      acc[mi][1] = __builtin_amdgcn_mfma_f32_16x16x32_f16(a[mi], b[1], acc[mi][1], 0, 0, 0);
    }
    __builtin_amdgcn_s_setprio(0);

    // ---- phase 1: ks0, ni 2-3 ----
    asm volatile("s_barrier" ::: "memory");
    b[2] = *(const f16x8*)(smem + dbuf + offB[2]);
    b[3] = *(const f16x8*)(smem + dbuf + offB[3]);
    STAGE_B(sdb, 32768, kbB);
    __builtin_amdgcn_s_setprio(1);
#pragma unroll
    for (int mi = 0; mi < 8; ++mi) {
      acc[mi][2] = __builtin_amdgcn_mfma_f32_16x16x32_f16(a[mi], b[2], acc[mi][2], 0, 0, 0);
      acc[mi][3] = __builtin_amdgcn_mfma_f32_16x16x32_f16(a[mi], b[3], acc[mi][3], 0, 0, 0);
    }
    __builtin_amdgcn_s_setprio(0);

    // ---- phase 2: ks1, ni 0-1 ----
    asm volatile("s_waitcnt vmcnt(4)" ::: "memory");
    asm volatile("s_barrier" ::: "memory");
#pragma unroll
    for (int mi = 0; mi < 8; ++mi) a[mi] = *(const f16x8*)(smem + dbuf + 16384 + offA[mi]);
    b[0] = *(const f16x8*)(smem + dbuf + 16384 + offB[0]);
    b[1] = *(const f16x8*)(smem + dbuf + 16384 + offB[1]);
    STAGE_A(sdb, 16384, kbA + 64);
    __builtin_amdgcn_s_setprio(1);
#pragma unroll
    for (int mi = 0; mi < 8; ++mi) {
      acc[mi][0] = __builtin_amdgcn_mfma_f32_16x16x32_f16(a[mi], b[0], acc[mi][0], 0, 0, 0);
      acc[mi][1] = __builtin_amdgcn_mfma_f32_16x16x32_f16(a[mi], b[1], acc[mi][1], 0, 0, 0);
    }
    __builtin_amdgcn_s_setprio(0);

    // ---- phase 3: ks1, ni 2-3 ----
    asm volatile("s_barrier" ::: "memory");
    b[2] = *(const f16x8*)(smem + dbuf + 16384 + offB[2]);
    b[3] = *(const f16x8*)(smem + dbuf + 16384 + offB[3]);
    STAGE_B(sdb, 49152, kbB + 64);
    __builtin_amdgcn_s_setprio(1);
#pragma unroll
    for (int mi = 0; mi < 8; ++mi) {
      acc[mi][2] = __builtin_amdgcn_mfma_f32_16x16x32_f16(a[mi], b[2], acc[mi][2], 0, 0, 0);
      acc[mi][3] = __builtin_amdgcn_mfma_f32_16x16x32_f16(a[mi], b[3], acc[mi][3], 0, 0, 0);
    }
    __builtin_amdgcn_s_setprio(0);
  }

  // drain tail junk stages, then LDS is ours for the epilogue
  asm volatile("s_waitcnt vmcnt(0)" ::: "memory");
  __syncthreads();

  // ---- epilogue: wave-private transpose -> per-row top-4 over 64-col stripe ----
  float rv[4];
#pragma unroll
  for (int ni = 0; ni < 4; ++ni) rv[ni] = r2g[n0 + wn * 64 + ni * 16 + ln15];
  float* sw = (float*)smem + wid * 2112;   // [32][66] f32, wave-private
  const int rr = lane >> 1, hh = lane & 1;
#pragma unroll
  for (int P = 0; P < 4; ++P) {
#pragma unroll
    for (int mh = 0; mh < 2; ++mh)
#pragma unroll
      for (int ni = 0; ni < 4; ++ni)
#pragma unroll
        for (int r = 0; r < 4; ++r) {
          const int row_l = mh * 16 + g4 * 4 + r;   // C/D: col=lane&15, row=(lane>>4)*4+reg
          sw[row_l * 66 + ni * 16 + ln15] = rv[ni] - 2.0f * acc[2 * P + mh][ni][r];
        }
    asm volatile("s_waitcnt lgkmcnt(0)" ::: "memory");
    __builtin_amdgcn_sched_barrier(0);
    float s[4]  = {1e30f, 1e30f, 1e30f, 1e30f};
    int   id[4] = {0x7fffffff, 0x7fffffff, 0x7fffffff, 0x7fffffff};
    const float* rowp = sw + rr * 66 + hh * 32;
    const int cb = n0 + wn * 64 + hh * 32;
#pragma unroll
    for (int j = 0; j < 16; ++j) {
      const float2 v = *(const float2*)(rowp + j * 2);
      insert4(s, id, v.x, cb + j * 2);
      insert4(s, id, v.y, cb + j * 2 + 1);
    }
    float os[4]; int oid[4];
#pragma unroll
    for (int j = 0; j < 4; ++j) { os[j] = __shfl_xor(s[j], 1); oid[j] = __shfl_xor(id[j], 1); }
    merge_top4(s, id, os, oid);
    if (hh == 0) {
      const int q = m0 + wm * 128 + P * 32 + rr;
      const int base = (q * NL + bx * 4 + wn) * 4;
#pragma unroll
      for (int j = 0; j < 4; ++j) { pscore[base + j] = s[j]; pidx[base + j] = id[j]; }
    }
    asm volatile("s_waitcnt lgkmcnt(0)" ::: "memory");
  }
#undef STAGE_A
#undef STAGE_B
}

// ---------- merge NLISTS partial lists per query -> final 4 indices ----------
template <int NLISTS>
__global__ __launch_bounds__(64)
void select_kernel(const float* __restrict__ pscore, const int* __restrict__ pidx,
                   int* __restrict__ final4) {
  const int t = blockIdx.x, lane = threadIdx.x;
  constexpr int LPL = NLISTS / 64;
  float s[4]  = {1e30f, 1e30f, 1e30f, 1e30f};
  int   id[4] = {0x7fffffff, 0x7fffffff, 0x7fffffff, 0x7fffffff};
#pragma unroll
  for (int li = 0; li < LPL; ++li) {
    const int base = (t * NLISTS + lane * LPL + li) * 4;
    const float4 sv = *(const float4*)&pscore[base];
    const int4   iv = *(const int4*)&pidx[base];
    float os[4] = {sv.x, sv.y, sv.z, sv.w};
    int  oid[4] = {iv.x, iv.y, iv.z, iv.w};
    merge_top4(s, id, os, oid);
  }
#pragma unroll
  for (int mask = 1; mask < 64; mask <<= 1) {
    float os[4]; int oid[4];
#pragma unroll
    for (int j = 0; j < 4; ++j) {
      os[j]  = __shfl_xor(s[j], mask);
      oid[j] = __shfl_xor(id[j], mask);
    }
    merge_top4(s, id, os, oid);
  }
  if (lane == 0) {
    int4 o; o.x = id[0]; o.y = id[1]; o.z = id[2]; o.w = id[3];
    *(int4*)&final4[t * 4] = o;
  }
}

// ---------- gather 4 neighbors, average, write [d][T] ----------
__global__ __launch_bounds__(256)
void gather_kernel(const float* __restrict__ R, const int* __restrict__ final4,
                   float* __restrict__ out) {
  __shared__ int ids[64][4];
  const int tx = threadIdx.x & 63, ty = threadIdx.x >> 6;
  const int t0 = blockIdx.x * 64;
  ((int*)ids)[threadIdx.x] = final4[t0 * 4 + threadIdx.x];
  __syncthreads();
  const int d = blockIdx.y * 4 + ty;
  const float* row = R + (size_t)d * N_REF;
  const float sum = row[ids[tx][0]] + row[ids[tx][1]] + row[ids[tx][2]] + row[ids[tx][3]];
  out[(size_t)d * T_Q + t0 + tx] = 0.25f * sum;
}

// ---------- fallback fp32 pipeline (round-1, known correct) ----------
#define FBM 64
#define FBN 256
#define FBK 16
#define FNL (N_REF / FBN)
__global__ __launch_bounds__(256)
void score_topk_kernel(const float* __restrict__ X, const float* __restrict__ R,
                       const float* __restrict__ r2,
                       float* __restrict__ pscore, int* __restrict__ pidx) {
  __shared__ float As[FBK][FBM];
  __shared__ float Bs[FBK][FBN];
  __shared__ float r2s[FBN];
  const int tid = threadIdx.x;
  const int tx = tid & 15, ty = tid >> 4;
  const int m0 = blockIdx.y * FBM;
  const int n0 = blockIdx.x * FBN;
  r2s[tid] = r2[n0 + tid];
  float acc[4][16];
#pragma unroll
  for (int i = 0; i < 4; ++i)
#pragma unroll
    for (int j = 0; j < 16; ++j) acc[i][j] = 0.f;
  for (int k0 = 0; k0 < DIM; k0 += FBK) {
    {
      const int k = tid >> 4, m4 = tid & 15;
      const float4 av = *(const float4*)&X[(size_t)(k0 + k) * T_Q + m0 + m4 * 4];
      *(float4*)&As[k][m4 * 4] = av;
    }
#pragma unroll
    for (int i = 0; i < 4; ++i) {
      const int idx4 = tid + i * 256;
      const int k = idx4 >> 6, n4 = idx4 & 63;
      const float4 bv = *(const float4*)&R[(size_t)(k0 + k) * N_REF + n0 + n4 * 4];
      *(float4*)&Bs[k][n4 * 4] = bv;
    }
    __syncthreads();
#pragma unroll
    for (int k = 0; k < FBK; ++k) {
      float av[4], bv[16];
      *(float4*)av = *(const float4*)&As[k][ty * 4];
#pragma unroll
      for (int c = 0; c < 4; ++c)
        *(float4*)&bv[c * 4] = *(const float4*)&Bs[k][tx * 4 + c * 64];
#pragma unroll
      for (int mi = 0; mi < 4; ++mi)
#pragma unroll
        for (int ni = 0; ni < 16; ++ni) acc[mi][ni] += av[mi] * bv[ni];
    }
    __syncthreads();
  }
#pragma unroll
  for (int mi = 0; mi < 4; ++mi) {
    float s[4]  = {1e30f, 1e30f, 1e30f, 1e30f};
    int   id[4] = {0x7fffffff, 0x7fffffff, 0x7fffffff, 0x7fffffff};
#pragma unroll
    for (int c = 0; c < 4; ++c)
#pragma unroll
      for (int j = 0; j < 4; ++j) {
        const int nl = tx * 4 + c * 64 + j;
        const float sc = r2s[nl] - 2.0f * acc[mi][c * 4 + j];
        insert4(s, id, sc, n0 + nl);
      }
#pragma unroll
    for (int mask = 1; mask < 16; mask <<= 1) {
      float os[4]; int oid[4];
#pragma unroll
      for (int j = 0; j < 4; ++j) {
        os[j]  = __shfl_xor(s[j], mask);
        oid[j] = __shfl_xor(id[j], mask);
      }
      merge_top4(s, id, os, oid);
    }
    if (tx == 0) {
      const int t = m0 + ty * 4 + mi;
      const int base = (t * FNL + (int)blockIdx.x) * 4;
#pragma unroll
      for (int j = 0; j < 4; ++j) { pscore[base + j] = s[j]; pidx[base + j] = id[j]; }
    }
  }
}

extern "C" void kernel_launch(void* const* d_in, const int* in_sizes, int n_in,
                              void* d_out, int out_size, void* d_ws, size_t ws_size,
                              hipStream_t stream) {
  const float* X = (const float*)d_in[0];   // [768][2048]
  const float* R = (const float*)d_in[1];   // [768][16384]
  float* out = (float*)d_out;               // [768][2048]

  const size_t szA2 = (size_t)T_Q * KP2 * sizeof(f16);       // 6,291,456
  const size_t szB2 = (size_t)N_REF * KP2 * sizeof(f16);     // 50,331,648
  const size_t szr2 = (size_t)N_REF * sizeof(float);         // 65,536
  const size_t szPS = (size_t)T_Q * NL * 4 * sizeof(float);  // 8,388,608
  const size_t need = szA2 + szB2 + szr2 + 2 * szPS + (size_t)T_Q * 4 * sizeof(int);

  if (ws_size >= need) {
    char* w = (char*)d_ws;
    f16* A2 = (f16*)w;            w += szA2;
    f16* B2 = (f16*)w;            w += szB2;
    float* r2     = (float*)w;    w += szr2;
    float* pscore = (float*)w;    w += szPS;
    int*   pidx   = (int*)w;      w += szPS;
    int*   final4 = (int*)w;

    hipLaunchKernelGGL(r2_kernel, dim3(N_REF / 64), dim3(256), 0, stream, R, r2);
    hipLaunchKernelGGL(tsplit_kernel, dim3(T_Q / 64, DIM / 64), dim3(256), 0, stream,
                       X, A2, T_Q);
    hipLaunchKernelGGL(tsplit_kernel, dim3(N_REF / 64, DIM / 64), dim3(256), 0, stream,
                       R, B2, N_REF);
    hipLaunchKernelGGL(mfma8_topk_kernel, dim3((N_REF / BN) * (T_Q / BM)), dim3(512), 0, stream,
                       A2, B2, r2, pscore, pidx);
    hipLaunchKernelGGL((select_kernel<NL>), dim3(T_Q), dim3(64), 0, stream,
                       pscore, pidx, final4);
    hipLaunchKernelGGL(gather_kernel, dim3(T_Q / 64, DIM / 4), dim3(256), 0, stream,
                       R, final4, out);
  } else {
    // fallback: fp32 pipeline (~4.2 MB ws)
    char* w = (char*)d_ws;
    float* r2     = (float*)w;  w += szr2;
    float* pscore = (float*)w;  w += (size_t)T_Q * FNL * 4 * sizeof(float);
    int*   pidx   = (int*)w;    w += (size_t)T_Q * FNL * 4 * sizeof(int);
    int*   final4 = (int*)w;

    hipLaunchKernelGGL(r2_kernel, dim3(N_REF / 64), dim3(256), 0, stream, R, r2);
    hipLaunchKernelGGL(score_topk_kernel, dim3(N_REF / FBN, T_Q / FBM), dim3(256), 0, stream,
                       X, R, r2, pscore, pidx);
    hipLaunchKernelGGL((select_kernel<FNL>), dim3(T_Q), dim3(64), 0, stream,
                       pscore, pidx, final4);
    hipLaunchKernelGGL(gather_kernel, dim3(T_Q / 64, DIM / 4), dim3(256), 0, stream,
                       R, final4, out);
  }
}

// Round 4
// 257.941 us; speedup vs baseline: 2.6835x; 1.0398x over previous
//
#include <hip/hip_runtime.h>
#include <stdint.h>

#define T_Q   2048
#define N_REF 16384
#define DIM   768
#define KP2   1536        // packed K cols: [hi | lo]
#define NT    36          // logical K' = 2304 = 36 tiles of 64
#define BM    256
#define BN    256
#define NL    256         // partial top-4 lists per query

using f16   = _Float16;
using f16x4 = __attribute__((ext_vector_type(4))) _Float16;
using f16x8 = __attribute__((ext_vector_type(8))) _Float16;
using f32x4 = __attribute__((ext_vector_type(4))) float;

// ---------- lexicographic top-4 helpers (static indices only) ----------
__device__ __forceinline__ bool lex_less(float sa, int ia, float sb, int ib) {
  return (sa < sb) || (sa == sb && ia < ib);
}
#define CE_PAIR(s0, i0, s1, i1)                                        \
  { if (lex_less(s1, i1, s0, i0)) { float _ts = s0; s0 = s1; s1 = _ts; \
                                    int _ti = i0; i0 = i1; i1 = _ti; } }
#define PICKMIN(as, ai, bs, bi, rs, ri)                   \
  { if (lex_less(bs, bi, as, ai)) { rs = bs; ri = bi; }   \
    else                          { rs = as; ri = ai; } }

__device__ __forceinline__ void insert4(float s[4], int id[4], float sc, int n) {
  if (lex_less(sc, n, s[3], id[3])) {
    s[3] = sc; id[3] = n;
    CE_PAIR(s[2], id[2], s[3], id[3]);
    CE_PAIR(s[1], id[1], s[2], id[2]);
    CE_PAIR(s[0], id[0], s[1], id[1]);
  }
}
__device__ __forceinline__ void merge_top4(float s[4], int id[4],
                                           const float os[4], const int oid[4]) {
  float l0, l1, l2, l3; int j0, j1, j2, j3;
  PICKMIN(s[0], id[0], os[3], oid[3], l0, j0);
  PICKMIN(s[1], id[1], os[2], oid[2], l1, j1);
  PICKMIN(s[2], id[2], os[1], oid[1], l2, j2);
  PICKMIN(s[3], id[3], os[0], oid[0], l3, j3);
  CE_PAIR(l0, j0, l2, j2);
  CE_PAIR(l1, j1, l3, j3);
  CE_PAIR(l0, j0, l1, j1);
  CE_PAIR(l2, j2, l3, j3);
  s[0] = l0; s[1] = l1; s[2] = l2; s[3] = l3;
  id[0] = j0; id[1] = j1; id[2] = j2; id[3] = j3;
}

__device__ __forceinline__ void gl_lds16(const void* g, void* l) {
  __builtin_amdgcn_global_load_lds((const __attribute__((address_space(1))) uint32_t*)g,
                                   (__attribute__((address_space(3))) uint32_t*)l, 16, 0, 0);
}

// ---------- r2[n] = ||ref_n||^2 (fp32 exact) ----------
__global__ __launch_bounds__(256)
void r2_kernel(const float* __restrict__ R, float* __restrict__ r2) {
  __shared__ float red[256];
  const int lane = threadIdx.x & 63;
  const int dg   = threadIdx.x >> 6;
  const int n    = blockIdx.x * 64 + lane;
  float acc = 0.f;
  const int d0 = dg * (DIM / 4), d1 = d0 + (DIM / 4);
  for (int d = d0; d < d1; ++d) {
    float v = R[(size_t)d * N_REF + n];
    acc += v * v;
  }
  red[threadIdx.x] = acc;
  __syncthreads();
  if (threadIdx.x < 64)
    r2[n] = red[lane] + red[lane + 64] + red[lane + 128] + red[lane + 192];
}

// ---------- transpose + f16 hi/lo split: in[D][W] -> out[W][1536] = [hi | lo] ----------
__global__ __launch_bounds__(256)
void tsplit_kernel(const float* __restrict__ in, f16* __restrict__ out, int W) {
  __shared__ f16 lh[64][66], ll[64][66];
  const int c0 = blockIdx.x * 64, d0 = blockIdx.y * 64;
  const int q = threadIdx.x & 15, p = threadIdx.x >> 4;
#pragma unroll
  for (int i = 0; i < 4; ++i) {
    const int dl = p + i * 16;
    const float4 v = *(const float4*)&in[(size_t)(d0 + dl) * W + c0 + q * 4];
    const f16 h0 = (f16)v.x, h1 = (f16)v.y, h2 = (f16)v.z, h3 = (f16)v.w;
    lh[q * 4 + 0][dl] = h0; ll[q * 4 + 0][dl] = (f16)(v.x - (float)h0);
    lh[q * 4 + 1][dl] = h1; ll[q * 4 + 1][dl] = (f16)(v.y - (float)h1);
    lh[q * 4 + 2][dl] = h2; ll[q * 4 + 2][dl] = (f16)(v.z - (float)h2);
    lh[q * 4 + 3][dl] = h3; ll[q * 4 + 3][dl] = (f16)(v.w - (float)h3);
  }
  __syncthreads();
  const int rl = threadIdx.x >> 2, seg = threadIdx.x & 3;
  f16* rowo = out + (size_t)(c0 + rl) * KP2 + d0;
#pragma unroll
  for (int j = 0; j < 4; ++j) {
    const int dd = seg * 16 + j * 4;
    f16x4 vh = *(const f16x4*)&lh[rl][dd];
    f16x4 vl = *(const f16x4*)&ll[rl][dd];
    *(f16x4*)&rowo[dd] = vh;
    *(f16x4*)&rowo[768 + dd] = vl;
  }
}

// ---------- 8-phase 256x256 MFMA GEMM (K'=2304 folded) + fused top-4 ----------
__global__ __launch_bounds__(512, 2)
void mfma8_topk_kernel(const f16* __restrict__ A2, const f16* __restrict__ B2,
                       const float* __restrict__ r2g,
                       float* __restrict__ pscore, int* __restrict__ pidx) {
  // LDS: dbuf d at d*65536; within dbuf: A-ks0 @0, A-ks1 @16384, B-ks0 @32768, B-ks1 @49152
  // each region: 256 rows x 32 K-cols f16 (64B rows); 16B slot swizzle: seg ^= (row>>1)&3
  __shared__ __align__(16) char smem[131072];
  const int tid  = threadIdx.x;
  const int lane = tid & 63, wid = tid >> 6;
  const int wm = wid >> 2, wn = wid & 3;
  const int ln15 = lane & 15, g4 = lane >> 4;

  // supertile XCD mapping: XCD x (= flat&7) owns bx in [8x, 8x+8), all by.
  // per-XCD per-K-step footprint ~512 KB -> L2-resident B/A panels.
  const int flat = (int)blockIdx.x;
  const int jj = flat >> 3;
  const int bx = (flat & 7) * 8 + (jj & 7);  // 0..63
  const int by = jj >> 3;                    // 0..7
  const int m0 = by * BM, n0 = bx * BN;

  // ---- staging descriptors: 2 gl_lds(16B) per thread per half-tile ----
  // LDS slot s: row = s>>2, seg = s&3 ; global seg' = seg ^ ((row>>1)&3) = seg ^ ((s>>3)&3)
  const int s0 = tid, s1 = tid + 512;
  const int r0 = s0 >> 2, r1 = s1 >> 2;
  const int c0b = (((s0 & 3) ^ ((s0 >> 3) & 3)) << 4);
  const int c1b = (((s1 & 3) ^ ((s1 >> 3) & 3)) << 4);
  const char* gA0 = (const char*)(A2 + (size_t)(m0 + r0) * KP2) + c0b;
  const char* gA1 = (const char*)(A2 + (size_t)(m0 + r1) * KP2) + c1b;
  const char* gB0 = (const char*)(B2 + (size_t)(n0 + r0) * KP2) + c0b;
  const char* gB1 = (const char*)(B2 + (size_t)(n0 + r1) * KP2) + c1b;
  const int l0 = s0 * 16, l1 = s1 * 16;  // linear LDS slots (wave-consecutive)

#define STAGE_A(sdb, regoff, kbyte)                              \
  { gl_lds16(gA0 + (kbyte), smem + (sdb) + (regoff) + l0);       \
    gl_lds16(gA1 + (kbyte), smem + (sdb) + (regoff) + l1); }
#define STAGE_B(sdb, regoff, kbyte)                              \
  { gl_lds16(gB0 + (kbyte), smem + (sdb) + (regoff) + l0);       \
    gl_lds16(gB1 + (kbyte), smem + (sdb) + (regoff) + l1); }

  // ---- fragment LDS offsets (K-invariant): lane needs global seg g4 of its row ----
  const int cswz = ((g4 ^ ((ln15 >> 1) & 3)) << 4);
  int offA[8], offB[4];
#pragma unroll
  for (int mi = 0; mi < 8; ++mi) offA[mi] = (wm * 128 + mi * 16 + ln15) * 64 + cswz;
#pragma unroll
  for (int ni = 0; ni < 4; ++ni) offB[ni] = 32768 + (wn * 64 + ni * 16 + ln15) * 64 + cswz;

  f32x4 acc[8][4] = {};

  // prologue: stage kt=0 (dbuf0), order A0,B0,A1,B1
  STAGE_A(0, 0, 0);
  STAGE_B(0, 32768, 0);
  STAGE_A(0, 16384, 64);
  STAGE_B(0, 49152, 64);

  for (int kt = 0; kt < NT; ++kt) {
    const int dbuf = (kt & 1) << 16;
    const int sdb  = ((kt + 1) & 1) << 16;
    const int ktn = kt + 1;
    int tA = ktn < 12 ? ktn : ktn - 12; tA = tA > 23 ? 23 : tA;      // [Xh|Xh|Xl] map
    const int tB = ktn < 24 ? ktn : ktn - 24;                        // [Rh|Rl|Rh] map
    const int kbA = tA * 128, kbB = tB * 128;
    f16x8 a[8], b[4];

    // ---- phase 0: ks0, ni 0-1 ----
    asm volatile("s_waitcnt vmcnt(4)" ::: "memory");
    asm volatile("s_barrier" ::: "memory");
#pragma unroll
    for (int mi = 0; mi < 8; ++mi) a[mi] = *(const f16x8*)(smem + dbuf + offA[mi]);
    b[0] = *(const f16x8*)(smem + dbuf + offB[0]);
    b[1] = *(const f16x8*)(smem + dbuf + offB[1]);
    STAGE_A(sdb, 0, kbA);
    __builtin_amdgcn_s_setprio(1);
#pragma unroll
    for (int mi = 0; mi < 8; ++mi) {
      acc[mi][0] = __builtin_amdgcn_mfma_f32_16x16x32_f16(a[mi], b[0], acc[mi][0], 0, 0, 0);
      acc[mi][1] = __builtin_amdgcn_mfma_f32_16x16x32_f16(a[mi], b[1], acc[mi][1], 0, 0, 0);
    }
    __builtin_amdgcn_s_setprio(0);

    // ---- phase 1: ks0, ni 2-3 ----
    asm volatile("s_barrier" ::: "memory");
    b[2] = *(const f16x8*)(smem + dbuf + offB[2]);
    b[3] = *(const f16x8*)(smem + dbuf + offB[3]);
    STAGE_B(sdb, 32768, kbB);
    __builtin_amdgcn_s_setprio(1);
#pragma unroll
    for (int mi = 0; mi < 8; ++mi) {
      acc[mi][2] = __builtin_amdgcn_mfma_f32_16x16x32_f16(a[mi], b[2], acc[mi][2], 0, 0, 0);
      acc[mi][3] = __builtin_amdgcn_mfma_f32_16x16x32_f16(a[mi], b[3], acc[mi][3], 0, 0, 0);
    }
    __builtin_amdgcn_s_setprio(0);

    // ---- phase 2: ks1, ni 0-1 ----
    asm volatile("s_waitcnt vmcnt(4)" ::: "memory");
    asm volatile("s_barrier" ::: "memory");
#pragma unroll
    for (int mi = 0; mi < 8; ++mi) a[mi] = *(const f16x8*)(smem + dbuf + 16384 + offA[mi]);
    b[0] = *(const f16x8*)(smem + dbuf + 16384 + offB[0]);
    b[1] = *(const f16x8*)(smem + dbuf + 16384 + offB[1]);
    STAGE_A(sdb, 16384, kbA + 64);
    __builtin_amdgcn_s_setprio(1);
#pragma unroll
    for (int mi = 0; mi < 8; ++mi) {
      acc[mi][0] = __builtin_amdgcn_mfma_f32_16x16x32_f16(a[mi], b[0], acc[mi][0], 0, 0, 0);
      acc[mi][1] = __builtin_amdgcn_mfma_f32_16x16x32_f16(a[mi], b[1], acc[mi][1], 0, 0, 0);
    }
    __builtin_amdgcn_s_setprio(0);

    // ---- phase 3: ks1, ni 2-3 ----
    asm volatile("s_barrier" ::: "memory");
    b[2] = *(const f16x8*)(smem + dbuf + 16384 + offB[2]);
    b[3] = *(const f16x8*)(smem + dbuf + 16384 + offB[3]);
    STAGE_B(sdb, 49152, kbB + 64);
    __builtin_amdgcn_s_setprio(1);
#pragma unroll
    for (int mi = 0; mi < 8; ++mi) {
      acc[mi][2] = __builtin_amdgcn_mfma_f32_16x16x32_f16(a[mi], b[2], acc[mi][2], 0, 0, 0);
      acc[mi][3] = __builtin_amdgcn_mfma_f32_16x16x32_f16(a[mi], b[3], acc[mi][3], 0, 0, 0);
    }
    __builtin_amdgcn_s_setprio(0);
  }

  // drain tail junk stages, then LDS is ours for the epilogue
  asm volatile("s_waitcnt vmcnt(0)" ::: "memory");
  __syncthreads();

  // ---- epilogue: wave-private transpose -> per-row top-4 over 64-col stripe ----
  float rv[4];
#pragma unroll
  for (int ni = 0; ni < 4; ++ni) rv[ni] = r2g[n0 + wn * 64 + ni * 16 + ln15];
  float* sw = (float*)smem + wid * 2112;   // [32][66] f32, wave-private
  const int rr = lane >> 1, hh = lane & 1;
#pragma unroll
  for (int P = 0; P < 4; ++P) {
#pragma unroll
    for (int mh = 0; mh < 2; ++mh)
#pragma unroll
      for (int ni = 0; ni < 4; ++ni)
#pragma unroll
        for (int r = 0; r < 4; ++r) {
          const int row_l = mh * 16 + g4 * 4 + r;   // C/D: col=lane&15, row=(lane>>4)*4+reg
          sw[row_l * 66 + ni * 16 + ln15] = rv[ni] - 2.0f * acc[2 * P + mh][ni][r];
        }
    asm volatile("s_waitcnt lgkmcnt(0)" ::: "memory");
    __builtin_amdgcn_sched_barrier(0);
    float s[4]  = {1e30f, 1e30f, 1e30f, 1e30f};
    int   id[4] = {0x7fffffff, 0x7fffffff, 0x7fffffff, 0x7fffffff};
    const float* rowp = sw + rr * 66 + hh * 32;
    const int cb = n0 + wn * 64 + hh * 32;
#pragma unroll
    for (int j = 0; j < 16; ++j) {
      const float2 v = *(const float2*)(rowp + j * 2);
      insert4(s, id, v.x, cb + j * 2);
      insert4(s, id, v.y, cb + j * 2 + 1);
    }
    float os[4]; int oid[4];
#pragma unroll
    for (int j = 0; j < 4; ++j) { os[j] = __shfl_xor(s[j], 1); oid[j] = __shfl_xor(id[j], 1); }
    merge_top4(s, id, os, oid);
    if (hh == 0) {
      const int q = m0 + wm * 128 + P * 32 + rr;
      const int base = (q * NL + bx * 4 + wn) * 4;
#pragma unroll
      for (int j = 0; j < 4; ++j) { pscore[base + j] = s[j]; pidx[base + j] = id[j]; }
    }
    asm volatile("s_waitcnt lgkmcnt(0)" ::: "memory");
  }
#undef STAGE_A
#undef STAGE_B
}

// ---------- merge NLISTS partial lists per query -> final 4 indices ----------
template <int NLISTS>
__global__ __launch_bounds__(64)
void select_kernel(const float* __restrict__ pscore, const int* __restrict__ pidx,
                   int* __restrict__ final4) {
  const int t = blockIdx.x, lane = threadIdx.x;
  constexpr int LPL = NLISTS / 64;
  float s[4]  = {1e30f, 1e30f, 1e30f, 1e30f};
  int   id[4] = {0x7fffffff, 0x7fffffff, 0x7fffffff, 0x7fffffff};
#pragma unroll
  for (int li = 0; li < LPL; ++li) {
    const int base = (t * NLISTS + lane * LPL + li) * 4;
    const float4 sv = *(const float4*)&pscore[base];
    const int4   iv = *(const int4*)&pidx[base];
    float os[4] = {sv.x, sv.y, sv.z, sv.w};
    int  oid[4] = {iv.x, iv.y, iv.z, iv.w};
    merge_top4(s, id, os, oid);
  }
#pragma unroll
  for (int mask = 1; mask < 64; mask <<= 1) {
    float os[4]; int oid[4];
#pragma unroll
    for (int j = 0; j < 4; ++j) {
      os[j]  = __shfl_xor(s[j], mask);
      oid[j] = __shfl_xor(id[j], mask);
    }
    merge_top4(s, id, os, oid);
  }
  if (lane == 0) {
    int4 o; o.x = id[0]; o.y = id[1]; o.z = id[2]; o.w = id[3];
    *(int4*)&final4[t * 4] = o;
  }
}

// ---------- gather 4 neighbors, average, write [d][T] ----------
__global__ __launch_bounds__(256)
void gather_kernel(const float* __restrict__ R, const int* __restrict__ final4,
                   float* __restrict__ out) {
  __shared__ int ids[64][4];
  const int tx = threadIdx.x & 63, ty = threadIdx.x >> 6;
  const int t0 = blockIdx.x * 64;
  ((int*)ids)[threadIdx.x] = final4[t0 * 4 + threadIdx.x];
  __syncthreads();
  const int d = blockIdx.y * 4 + ty;
  const float* row = R + (size_t)d * N_REF;
  const float sum = row[ids[tx][0]] + row[ids[tx][1]] + row[ids[tx][2]] + row[ids[tx][3]];
  out[(size_t)d * T_Q + t0 + tx] = 0.25f * sum;
}

// ---------- fallback fp32 pipeline (round-1, known correct) ----------
#define FBM 64
#define FBN 256
#define FBK 16
#define FNL (N_REF / FBN)
__global__ __launch_bounds__(256)
void score_topk_kernel(const float* __restrict__ X, const float* __restrict__ R,
                       const float* __restrict__ r2,
                       float* __restrict__ pscore, int* __restrict__ pidx) {
  __shared__ float As[FBK][FBM];
  __shared__ float Bs[FBK][FBN];
  __shared__ float r2s[FBN];
  const int tid = threadIdx.x;
  const int tx = tid & 15, ty = tid >> 4;
  const int m0 = blockIdx.y * FBM;
  const int n0 = blockIdx.x * FBN;
  r2s[tid] = r2[n0 + tid];
  float acc[4][16];
#pragma unroll
  for (int i = 0; i < 4; ++i)
#pragma unroll
    for (int j = 0; j < 16; ++j) acc[i][j] = 0.f;
  for (int k0 = 0; k0 < DIM; k0 += FBK) {
    {
      const int k = tid >> 4, m4 = tid & 15;
      const float4 av = *(const float4*)&X[(size_t)(k0 + k) * T_Q + m0 + m4 * 4];
      *(float4*)&As[k][m4 * 4] = av;
    }
#pragma unroll
    for (int i = 0; i < 4; ++i) {
      const int idx4 = tid + i * 256;
      const int k = idx4 >> 6, n4 = idx4 & 63;
      const float4 bv = *(const float4*)&R[(size_t)(k0 + k) * N_REF + n0 + n4 * 4];
      *(float4*)&Bs[k][n4 * 4] = bv;
    }
    __syncthreads();
#pragma unroll
    for (int k = 0; k < FBK; ++k) {
      float av[4], bv[16];
      *(float4*)av = *(const float4*)&As[k][ty * 4];
#pragma unroll
      for (int c = 0; c < 4; ++c)
        *(float4*)&bv[c * 4] = *(const float4*)&Bs[k][tx * 4 + c * 64];
#pragma unroll
      for (int mi = 0; mi < 4; ++mi)
#pragma unroll
        for (int ni = 0; ni < 16; ++ni) acc[mi][ni] += av[mi] * bv[ni];
    }
    __syncthreads();
  }
#pragma unroll
  for (int mi = 0; mi < 4; ++mi) {
    float s[4]  = {1e30f, 1e30f, 1e30f, 1e30f};
    int   id[4] = {0x7fffffff, 0x7fffffff, 0x7fffffff, 0x7fffffff};
#pragma unroll
    for (int c = 0; c < 4; ++c)
#pragma unroll
      for (int j = 0; j < 4; ++j) {
        const int nl = tx * 4 + c * 64 + j;
        const float sc = r2s[nl] - 2.0f * acc[mi][c * 4 + j];
        insert4(s, id, sc, n0 + nl);
      }
#pragma unroll
    for (int mask = 1; mask < 16; mask <<= 1) {
      float os[4]; int oid[4];
#pragma unroll
      for (int j = 0; j < 4; ++j) {
        os[j]  = __shfl_xor(s[j], mask);
        oid[j] = __shfl_xor(id[j], mask);
      }
      merge_top4(s, id, os, oid);
    }
    if (tx == 0) {
      const int t = m0 + ty * 4 + mi;
      const int base = (t * FNL + (int)blockIdx.x) * 4;
#pragma unroll
      for (int j = 0; j < 4; ++j) { pscore[base + j] = s[j]; pidx[base + j] = id[j]; }
    }
  }
}

extern "C" void kernel_launch(void* const* d_in, const int* in_sizes, int n_in,
                              void* d_out, int out_size, void* d_ws, size_t ws_size,
                              hipStream_t stream) {
  const float* X = (const float*)d_in[0];   // [768][2048]
  const float* R = (const float*)d_in[1];   // [768][16384]
  float* out = (float*)d_out;               // [768][2048]

  const size_t szA2 = (size_t)T_Q * KP2 * sizeof(f16);       // 6,291,456
  const size_t szB2 = (size_t)N_REF * KP2 * sizeof(f16);     // 50,331,648
  const size_t szr2 = (size_t)N_REF * sizeof(float);         // 65,536
  const size_t szPS = (size_t)T_Q * NL * 4 * sizeof(float);  // 8,388,608
  const size_t need = szA2 + szB2 + szr2 + 2 * szPS + (size_t)T_Q * 4 * sizeof(int);

  if (ws_size >= need) {
    char* w = (char*)d_ws;
    f16* A2 = (f16*)w;            w += szA2;
    f16* B2 = (f16*)w;            w += szB2;
    float* r2     = (float*)w;    w += szr2;
    float* pscore = (float*)w;    w += szPS;
    int*   pidx   = (int*)w;      w += szPS;
    int*   final4 = (int*)w;

    hipLaunchKernelGGL(r2_kernel, dim3(N_REF / 64), dim3(256), 0, stream, R, r2);
    hipLaunchKernelGGL(tsplit_kernel, dim3(T_Q / 64, DIM / 64), dim3(256), 0, stream,
                       X, A2, T_Q);
    hipLaunchKernelGGL(tsplit_kernel, dim3(N_REF / 64, DIM / 64), dim3(256), 0, stream,
                       R, B2, N_REF);
    hipLaunchKernelGGL(mfma8_topk_kernel, dim3((N_REF / BN) * (T_Q / BM)), dim3(512), 0, stream,
                       A2, B2, r2, pscore, pidx);
    hipLaunchKernelGGL((select_kernel<NL>), dim3(T_Q), dim3(64), 0, stream,
                       pscore, pidx, final4);
    hipLaunchKernelGGL(gather_kernel, dim3(T_Q / 64, DIM / 4), dim3(256), 0, stream,
                       R, final4, out);
  } else {
    // fallback: fp32 pipeline (~4.2 MB ws)
    char* w = (char*)d_ws;
    float* r2     = (float*)w;  w += szr2;
    float* pscore = (float*)w;  w += (size_t)T_Q * FNL * 4 * sizeof(float);
    int*   pidx   = (int*)w;    w += (size_t)T_Q * FNL * 4 * sizeof(int);
    int*   final4 = (int*)w;

    hipLaunchKernelGGL(r2_kernel, dim3(N_REF / 64), dim3(256), 0, stream, R, r2);
    hipLaunchKernelGGL(score_topk_kernel, dim3(N_REF / FBN, T_Q / FBM), dim3(256), 0, stream,
                       X, R, r2, pscore, pidx);
    hipLaunchKernelGGL((select_kernel<FNL>), dim3(T_Q), dim3(64), 0, stream,
                       pscore, pidx, final4);
    hipLaunchKernelGGL(gather_kernel, dim3(T_Q / 64, DIM / 4), dim3(256), 0, stream,
                       R, final4, out);
  }
}